// Round 1
// baseline (1709.054 us; speedup 1.0000x reference)
//
#include <hip/hip_runtime.h>

constexpr int NN   = 131072;   // total nodes
constexpr int PP   = 4096;     // nodes per graph
constexpr int BG   = 32;       // graphs
constexpr int EE   = 2097152;  // edges
constexpr int IND  = 64;
constexpr int HH   = 128;
constexpr int OUTD = 16;
constexpr float EPSV   = 1e-5f;
constexpr float SLOPEV = 0.01f;

// ---------------- degree count ----------------
__global__ void k_deg(const int* __restrict__ src, const int* __restrict__ dst,
                      int* __restrict__ degs, int* __restrict__ degd) {
    int e = blockIdx.x * 256 + threadIdx.x;          // grid exactly covers EE
    atomicAdd(&degs[src[e]], 1);
    atomicAdd(&degd[dst[e]], 1);
}

__global__ void k_rsqrt(const int* __restrict__ degs, const int* __restrict__ degd,
                        float* __restrict__ rss, float* __restrict__ rsd) {
    int v = blockIdx.x * 256 + threadIdx.x;
    int a = degs[v]; if (a < 1) a = 1;
    int b = degd[v]; if (b < 1) b = 1;
    rss[v] = rsqrtf((float)a);
    rsd[v] = rsqrtf((float)b);
}

// ---------------- exclusive scan of dst-degrees (single block) ----------------
__global__ void k_scan(const int* __restrict__ degd, int* __restrict__ offs,
                       int* __restrict__ cursor) {
    __shared__ int sums[1024];
    int t = threadIdx.x;
    const int CH = NN / 1024;                        // 128
    int base = t * CH;
    int s = 0;
    for (int i = 0; i < CH; i++) s += degd[base + i];
    sums[t] = s;
    __syncthreads();
    for (int off = 1; off < 1024; off <<= 1) {
        int v = sums[t];
        int add = (t >= off) ? sums[t - off] : 0;
        __syncthreads();
        sums[t] = v + add;
        __syncthreads();
    }
    int run = (t == 0) ? 0 : sums[t - 1];
    for (int i = 0; i < CH; i++) {
        offs[base + i]   = run;
        cursor[base + i] = run;
        run += degd[base + i];
    }
}

// ---------------- bucket edges by dst, packing (src, w) ----------------
__global__ void k_scatter(const int* __restrict__ src, const int* __restrict__ dst,
                          const float* __restrict__ ew, const float* __restrict__ rss,
                          int* __restrict__ cursor, float2* __restrict__ csr) {
    int e = blockIdx.x * 256 + threadIdx.x;
    int s = src[e], d = dst[e];
    float w = ew[e] * rss[s];
    int pos = atomicAdd(&cursor[d], 1);
    csr[pos] = make_float2(__int_as_float(s), w);
}

// ---------------- aggregation: wave per node, lane per feature ----------------
__global__ __launch_bounds__(256) void k_agg1(const float* __restrict__ x,
                                              const float2* __restrict__ csr,
                                              const int* __restrict__ offs,
                                              const int* __restrict__ degd,
                                              const float* __restrict__ rsd,
                                              float* __restrict__ m1) {
    int lane = threadIdx.x & 63;
    int v = (blockIdx.x * 256 + threadIdx.x) >> 6;
    int o = offs[v], cnt = degd[v];
    float acc = 0.f;
    for (int i = 0; i < cnt; i++) {
        float2 p = csr[o + i];
        int s = __float_as_int(p.x);
        acc += p.y * x[s * IND + lane];
    }
    m1[v * IND + lane] = acc * rsd[v];
}

__global__ __launch_bounds__(256) void k_agg2(const float* __restrict__ h1,
                                              const float2* __restrict__ csr,
                                              const int* __restrict__ offs,
                                              const int* __restrict__ degd,
                                              const float* __restrict__ rsd,
                                              float* __restrict__ m2) {
    int lane = threadIdx.x & 63;
    int v = (blockIdx.x * 256 + threadIdx.x) >> 6;
    int o = offs[v], cnt = degd[v];
    float a0 = 0.f, a1 = 0.f;
    for (int i = 0; i < cnt; i++) {
        float2 p = csr[o + i];
        const float* hp = h1 + (size_t)__float_as_int(p.x) * HH;
        a0 += p.y * hp[lane];
        a1 += p.y * hp[lane + 64];
    }
    float rd = rsd[v];
    m2[(size_t)v * HH + lane]      = a0 * rd;
    m2[(size_t)v * HH + 64 + lane] = a1 * rd;
}

// ---------------- GEMMs: thread per node, rows in VGPRs, W via scalar loads ----------------
__global__ __launch_bounds__(256) void k_gemm1(const float* __restrict__ m1,
                                               const float* __restrict__ W,
                                               float* __restrict__ out) {
    int n = blockIdx.x * 256 + threadIdx.x;
    float row[IND];
    const float4* rp = (const float4*)(m1 + (size_t)n * IND);
#pragma unroll
    for (int i = 0; i < IND / 4; i++) {
        float4 t = rp[i];
        row[4*i+0] = t.x; row[4*i+1] = t.y; row[4*i+2] = t.z; row[4*i+3] = t.w;
    }
    for (int fc = 0; fc < HH; fc += 16) {
        float acc[16];
#pragma unroll
        for (int j = 0; j < 16; j++) acc[j] = 0.f;
#pragma unroll
        for (int k = 0; k < IND; k++) {
            float a = row[k];
            const float4* wp = (const float4*)(W + k * HH + fc);  // wave-uniform -> s_load
            float4 w0 = wp[0], w1 = wp[1], w2 = wp[2], w3 = wp[3];
            acc[0]+=a*w0.x;  acc[1]+=a*w0.y;  acc[2]+=a*w0.z;  acc[3]+=a*w0.w;
            acc[4]+=a*w1.x;  acc[5]+=a*w1.y;  acc[6]+=a*w1.z;  acc[7]+=a*w1.w;
            acc[8]+=a*w2.x;  acc[9]+=a*w2.y;  acc[10]+=a*w2.z; acc[11]+=a*w2.w;
            acc[12]+=a*w3.x; acc[13]+=a*w3.y; acc[14]+=a*w3.z; acc[15]+=a*w3.w;
        }
        float4* op = (float4*)(out + (size_t)n * HH + fc);
        op[0] = make_float4(acc[0],  acc[1],  acc[2],  acc[3]);
        op[1] = make_float4(acc[4],  acc[5],  acc[6],  acc[7]);
        op[2] = make_float4(acc[8],  acc[9],  acc[10], acc[11]);
        op[3] = make_float4(acc[12], acc[13], acc[14], acc[15]);
    }
}

__global__ __launch_bounds__(256) void k_gemm2(const float* __restrict__ m2,
                                               const float* __restrict__ W,
                                               float* __restrict__ out) {
    int n = blockIdx.x * 256 + threadIdx.x;
    float r0[64], r1[64];
    const float4* rp = (const float4*)(m2 + (size_t)n * HH);
#pragma unroll
    for (int i = 0; i < 16; i++) {
        float4 t = rp[i];
        r0[4*i+0] = t.x; r0[4*i+1] = t.y; r0[4*i+2] = t.z; r0[4*i+3] = t.w;
    }
#pragma unroll
    for (int i = 0; i < 16; i++) {
        float4 t = rp[16 + i];
        r1[4*i+0] = t.x; r1[4*i+1] = t.y; r1[4*i+2] = t.z; r1[4*i+3] = t.w;
    }
    for (int fc = 0; fc < HH; fc += 16) {
        float acc[16];
#pragma unroll
        for (int j = 0; j < 16; j++) acc[j] = 0.f;
#pragma unroll
        for (int k = 0; k < 64; k++) {
            float a = r0[k];
            const float4* wp = (const float4*)(W + k * HH + fc);
            float4 w0 = wp[0], w1 = wp[1], w2 = wp[2], w3 = wp[3];
            acc[0]+=a*w0.x;  acc[1]+=a*w0.y;  acc[2]+=a*w0.z;  acc[3]+=a*w0.w;
            acc[4]+=a*w1.x;  acc[5]+=a*w1.y;  acc[6]+=a*w1.z;  acc[7]+=a*w1.w;
            acc[8]+=a*w2.x;  acc[9]+=a*w2.y;  acc[10]+=a*w2.z; acc[11]+=a*w2.w;
            acc[12]+=a*w3.x; acc[13]+=a*w3.y; acc[14]+=a*w3.z; acc[15]+=a*w3.w;
        }
#pragma unroll
        for (int k = 0; k < 64; k++) {
            float a = r1[k];
            const float4* wp = (const float4*)(W + (64 + k) * HH + fc);
            float4 w0 = wp[0], w1 = wp[1], w2 = wp[2], w3 = wp[3];
            acc[0]+=a*w0.x;  acc[1]+=a*w0.y;  acc[2]+=a*w0.z;  acc[3]+=a*w0.w;
            acc[4]+=a*w1.x;  acc[5]+=a*w1.y;  acc[6]+=a*w1.z;  acc[7]+=a*w1.w;
            acc[8]+=a*w2.x;  acc[9]+=a*w2.y;  acc[10]+=a*w2.z; acc[11]+=a*w2.w;
            acc[12]+=a*w3.x; acc[13]+=a*w3.y; acc[14]+=a*w3.z; acc[15]+=a*w3.w;
        }
        float4* op = (float4*)(out + (size_t)n * HH + fc);
        op[0] = make_float4(acc[0],  acc[1],  acc[2],  acc[3]);
        op[1] = make_float4(acc[4],  acc[5],  acc[6],  acc[7]);
        op[2] = make_float4(acc[8],  acc[9],  acc[10], acc[11]);
        op[3] = make_float4(acc[12], acc[13], acc[14], acc[15]);
    }
}

// ---------------- per-feature column sums (for GraphNorm stats) ----------------
__global__ __launch_bounds__(256) void k_colstats(const float* __restrict__ h,
                                                  float* __restrict__ S1,
                                                  float* __restrict__ S2) {
    int f = threadIdx.x & (HH - 1);
    int half = threadIdx.x >> 7;
    int rbase = blockIdx.x * 256;
    float s1 = 0.f, s2 = 0.f;
    for (int r = half; r < 256; r += 2) {
        float v = h[(size_t)(rbase + r) * HH + f];
        s1 += v; s2 += v * v;
    }
    __shared__ float sh[256];
    sh[threadIdx.x] = s1;
    __syncthreads();
    float t1 = (half == 0) ? s1 + sh[threadIdx.x + 128] : 0.f;
    __syncthreads();
    sh[threadIdx.x] = s2;
    __syncthreads();
    if (half == 0) {
        float t2 = s2 + sh[threadIdx.x + 128];
        atomicAdd(&S1[f], t1);
        atomicAdd(&S2[f], t2);
    }
}

__global__ void k_coef(const float* __restrict__ S1, const float* __restrict__ S2,
                       const float* __restrict__ gamma, const float* __restrict__ beta,
                       const float* __restrict__ alpha, float* __restrict__ ab) {
    int f = threadIdx.x;   // 128 threads
    float mu = S1[f] * (1.f / NN);
    float e2 = S2[f] * (1.f / NN);
    float al = alpha[f];
    float var = e2 - (2.f * al - al * al) * mu * mu;
    float a = rsqrtf(var + EPSV) * gamma[f];
    ab[f] = a;
    ab[HH + f] = beta[f] - al * mu * a;
}

// ---------------- fused norm + leaky-relu (+optional writeback) + per-graph readout ----------------
template <bool WRITE>
__global__ __launch_bounds__(256) void k_norm_readout(float* __restrict__ h,
                                                      const float* __restrict__ ab,
                                                      float* __restrict__ racc) {
    int f = threadIdx.x & (HH - 1);
    int half = threadIdx.x >> 7;
    int node0 = blockIdx.x * 64;           // 64 | 4096 -> block stays in one graph
    int g = node0 / PP;
    float a = ab[f], b = ab[HH + f];
    float s = 0.f;
    for (int i = half; i < 64; i += 2) {
        size_t idx = (size_t)(node0 + i) * HH + f;
        float v = fmaf(a, h[idx], b);
        v = v > 0.f ? v : SLOPEV * v;
        if (WRITE) h[idx] = v;
        s += v;
    }
    __shared__ float sh[256];
    sh[threadIdx.x] = s;
    __syncthreads();
    if (half == 0) atomicAdd(&racc[g * HH + f], s + sh[threadIdx.x + 128]);
}

// ---------------- final tiny GEMM: [B,2H] @ Wc^T ----------------
__global__ void k_final(const float* __restrict__ racc1, const float* __restrict__ racc2,
                        const float* __restrict__ Wc, float* __restrict__ out) {
    int t = threadIdx.x;        // 512 = 32*16
    int b = t >> 4, o = t & 15;
    float acc = 0.f;
    for (int f = 0; f < HH; f++) acc += racc1[b * HH + f] * Wc[o * (2 * HH) + f];
    for (int f = 0; f < HH; f++) acc += racc2[b * HH + f] * Wc[o * (2 * HH) + HH + f];
    out[t] = acc * (1.f / PP);
}

extern "C" void kernel_launch(void* const* d_in, const int* in_sizes, int n_in,
                              void* d_out, int out_size, void* d_ws, size_t ws_size,
                              hipStream_t stream) {
    const float* features = (const float*)d_in[0];
    const float* ew       = (const float*)d_in[1];
    const int*   src      = (const int*)d_in[2];
    const int*   dst      = (const int*)d_in[3];
    const float* W1       = (const float*)d_in[4];
    const float* W2       = (const float*)d_in[5];
    const float* Wc       = (const float*)d_in[6];
    const float* gamma1   = (const float*)d_in[7];
    const float* beta1    = (const float*)d_in[8];
    const float* alpha1   = (const float*)d_in[9];
    const float* gamma2   = (const float*)d_in[10];
    const float* beta2    = (const float*)d_in[11];
    const float* alpha2   = (const float*)d_in[12];
    float* out = (float*)d_out;

    char* w = (char*)d_ws;
    int*    deg_s  = (int*)(w + (0u   << 10));
    int*    deg_d  = (int*)(w + (512u << 10));
    float*  rs_s   = (float*)(w + (1024u << 10));
    float*  rs_d   = (float*)(w + (1536u << 10));
    int*    offs   = (int*)(w + (2048u << 10));
    int*    cursor = (int*)(w + (2560u << 10));
    float*  S1a    = (float*)(w + (3072u << 10));
    float*  S2a    = S1a + 128;
    float*  S1b    = S1a + 256;
    float*  S2b    = S1a + 384;
    float*  racc1  = S1a + 512;
    float*  racc2  = racc1 + BG * HH;
    float*  ab1    = racc2 + BG * HH;
    float*  ab2    = ab1 + 2 * HH;
    float2* csr    = (float2*)(w + (4u  << 20));   // 16 MB
    float*  R1     = (float*)(w + (20u << 20));    // 64 MB: m1 -> m2
    float*  R2     = (float*)(w + (84u << 20));    // 64 MB: h1pre -> h1 ; then h2pre

    // zero the atomic targets (ws is poisoned 0xAA before every call)
    hipMemsetAsync(deg_s, 0, 2 * NN * sizeof(int), stream);
    hipMemsetAsync(S1a, 0, (512 + 2 * BG * HH) * sizeof(float), stream);

    k_deg<<<EE / 256, 256, 0, stream>>>(src, dst, deg_s, deg_d);
    k_rsqrt<<<NN / 256, 256, 0, stream>>>(deg_s, deg_d, rs_s, rs_d);
    k_scan<<<1, 1024, 0, stream>>>(deg_d, offs, cursor);
    k_scatter<<<EE / 256, 256, 0, stream>>>(src, dst, ew, rs_s, cursor, csr);

    // ---- layer 1 ----
    k_agg1<<<NN / 4, 256, 0, stream>>>(features, csr, offs, deg_d, rs_d, R1);
    k_gemm1<<<NN / 256, 256, 0, stream>>>(R1, W1, R2);
    k_colstats<<<NN / 256, 256, 0, stream>>>(R2, S1a, S2a);
    k_coef<<<1, HH, 0, stream>>>(S1a, S2a, gamma1, beta1, alpha1, ab1);
    k_norm_readout<true><<<NN / 64, 256, 0, stream>>>(R2, ab1, racc1);

    // ---- layer 2 ----
    k_agg2<<<NN / 4, 256, 0, stream>>>(R2, csr, offs, deg_d, rs_d, R1);
    k_gemm2<<<NN / 256, 256, 0, stream>>>(R1, W2, R2);
    k_colstats<<<NN / 256, 256, 0, stream>>>(R2, S1b, S2b);
    k_coef<<<1, HH, 0, stream>>>(S1b, S2b, gamma2, beta2, alpha2, ab2);
    k_norm_readout<false><<<NN / 64, 256, 0, stream>>>(R2, ab2, racc2);

    // ---- readout head ----
    k_final<<<1, 512, 0, stream>>>(racc1, racc2, Wc, out);
}

// Round 2
// 820.626 us; speedup vs baseline: 2.0826x; 2.0826x over previous
//
#include <hip/hip_runtime.h>

constexpr int NN   = 131072;   // total nodes
constexpr int PP   = 4096;     // nodes per graph
constexpr int BG   = 32;       // graphs
constexpr int EE   = 2097152;  // edges
constexpr int IND  = 64;
constexpr int HH   = 128;
constexpr float EPSV   = 1e-5f;
constexpr float SLOPEV = 0.01f;

typedef short bf16x8 __attribute__((ext_vector_type(8)));
typedef float f32x4  __attribute__((ext_vector_type(4)));

__device__ __forceinline__ unsigned f2bf(float f) {
    unsigned u = __float_as_uint(f);
    return (u + 0x7FFFu + ((u >> 16) & 1u)) >> 16;      // RNE
}
__device__ __forceinline__ unsigned pack2bf(float lo, float hi) {
    return f2bf(lo) | (f2bf(hi) << 16);
}
__device__ __forceinline__ float bflo(unsigned p) { return __uint_as_float(p << 16); }
__device__ __forceinline__ float bfhi(unsigned p) { return __uint_as_float(p & 0xFFFF0000u); }

// ---------------- fp32 -> bf16-pair convert (features) ----------------
__global__ __launch_bounds__(256) void k_cvt(const float* __restrict__ in,
                                             unsigned* __restrict__ out) {
    int t = blockIdx.x * 256 + threadIdx.x;            // grid covers NN*IND/2
    float2 v = ((const float2*)in)[t];
    out[t] = pack2bf(v.x, v.y);
}

// ---------------- W -> MFMA B-fragment prepack ----------------
// frag order: pw[((kt*8+nt)*64+lane)*8 + j] = bf16( W[kt*32 + (lane>>4)*8 + j][nt*16 + (lane&15)] )
template <int K>
__global__ void k_packw(const float* __restrict__ W, unsigned short* __restrict__ pw) {
    int t = blockIdx.x * 256 + threadIdx.x;
    if (t >= K * 16) return;
    int lane = t & 63, nt = (t >> 6) & 7, kt = t >> 9;
    int kbase = kt * 32 + ((lane >> 4) & 3) * 8;
    int col   = nt * 16 + (lane & 15);
    for (int j = 0; j < 8; j++)
        pw[t * 8 + j] = (unsigned short)f2bf(W[(kbase + j) * HH + col]);
}

// ---------------- degrees ----------------
__global__ void k_deg(const int* __restrict__ src, const int* __restrict__ dst,
                      int* __restrict__ degs, int* __restrict__ degd) {
    int e = blockIdx.x * 256 + threadIdx.x;
    atomicAdd(&degs[src[e]], 1);
    atomicAdd(&degd[dst[e]], 1);
}

__global__ void k_rsqrt(const int* __restrict__ degs, const int* __restrict__ degd,
                        float* __restrict__ rss, float* __restrict__ rsd) {
    int v = blockIdx.x * 256 + threadIdx.x;
    int a = degs[v]; if (a < 1) a = 1;
    int b = degd[v]; if (b < 1) b = 1;
    rss[v] = rsqrtf((float)a);
    rsd[v] = rsqrtf((float)b);
}

// ---------------- exclusive scan of dst-degrees (single block) ----------------
__global__ void k_scan(const int* __restrict__ degd, int* __restrict__ offs,
                       int* __restrict__ cursor) {
    __shared__ int sums[1024];
    int t = threadIdx.x;
    const int CH = NN / 1024;
    int base = t * CH;
    int s = 0;
    for (int i = 0; i < CH; i++) s += degd[base + i];
    sums[t] = s;
    __syncthreads();
    for (int off = 1; off < 1024; off <<= 1) {
        int v = sums[t];
        int add = (t >= off) ? sums[t - off] : 0;
        __syncthreads();
        sums[t] = v + add;
        __syncthreads();
    }
    int run = (t == 0) ? 0 : sums[t - 1];
    for (int i = 0; i < CH; i++) {
        offs[base + i]   = run;
        cursor[base + i] = run;
        run += degd[base + i];
    }
}

// ---------------- bucket edges by dst ----------------
__global__ void k_scatter(const int* __restrict__ src, const int* __restrict__ dst,
                          const float* __restrict__ ew, const float* __restrict__ rss,
                          int* __restrict__ cursor, float2* __restrict__ csr) {
    int e = blockIdx.x * 256 + threadIdx.x;
    int s = src[e], d = dst[e];
    float w = ew[e] * rss[s];
    int pos = atomicAdd(&cursor[d], 1);
    csr[pos] = make_float2(__int_as_float(s), w);
}

// ---------------- agg layer 1: half-wave per node, bf16 gather, bf16 out ----------------
__global__ __launch_bounds__(256) void k_agg1(const unsigned* __restrict__ fx,   // [NN*32]
                                              const float2* __restrict__ csr,
                                              const int* __restrict__ offs,
                                              const int* __restrict__ degd,
                                              const float* __restrict__ rsd,
                                              unsigned* __restrict__ m1) {      // [NN*32]
    int bid = blockIdx.x;                       // NN/8 blocks
    int xcd = bid & 7, idx = bid >> 3;          // idx 0..2047
    int g = xcd * 4 + (idx >> 9);               // XCD x owns graphs 4x..4x+3
    int node0 = g * PP + (idx & 511) * 8;
    int lane = threadIdx.x & 63, wv = threadIdx.x >> 6;
    int half = lane >> 5, sl = lane & 31;
    int v = node0 + wv * 2 + half;
    int o = offs[v], cnt = degd[v];
    float ax0 = 0.f, ay0 = 0.f, ax1 = 0.f, ay1 = 0.f;
    int i = 0;
    for (; i + 4 <= cnt; i += 4) {
        float2 p0 = csr[o + i],     p1 = csr[o + i + 1];
        float2 p2 = csr[o + i + 2], p3 = csr[o + i + 3];
        unsigned g0 = fx[(size_t)__float_as_int(p0.x) * 32 + sl];
        unsigned g1 = fx[(size_t)__float_as_int(p1.x) * 32 + sl];
        unsigned g2 = fx[(size_t)__float_as_int(p2.x) * 32 + sl];
        unsigned g3 = fx[(size_t)__float_as_int(p3.x) * 32 + sl];
        ax0 += p0.y * bflo(g0); ay0 += p0.y * bfhi(g0);
        ax1 += p1.y * bflo(g1); ay1 += p1.y * bfhi(g1);
        ax0 += p2.y * bflo(g2); ay0 += p2.y * bfhi(g2);
        ax1 += p3.y * bflo(g3); ay1 += p3.y * bfhi(g3);
    }
    for (; i < cnt; i++) {
        float2 p = csr[o + i];
        unsigned g0 = fx[(size_t)__float_as_int(p.x) * 32 + sl];
        ax0 += p.y * bflo(g0); ay0 += p.y * bfhi(g0);
    }
    float rd = rsd[v];
    m1[(size_t)v * 32 + sl] = pack2bf((ax0 + ax1) * rd, (ay0 + ay1) * rd);
}

// ---------------- agg layer 2: wave per node ----------------
__global__ __launch_bounds__(256) void k_agg2(const unsigned* __restrict__ h1,   // [NN*64]
                                              const float2* __restrict__ csr,
                                              const int* __restrict__ offs,
                                              const int* __restrict__ degd,
                                              const float* __restrict__ rsd,
                                              unsigned* __restrict__ m2) {       // [NN*64]
    int bid = blockIdx.x;                        // NN/4 blocks
    int xcd = bid & 7, idx = bid >> 3;           // idx 0..4095
    int g = xcd * 4 + (idx >> 10);
    int node0 = g * PP + (idx & 1023) * 4;
    int lane = threadIdx.x & 63, wv = threadIdx.x >> 6;
    int v = node0 + wv;
    int o = offs[v], cnt = degd[v];
    float ax0 = 0.f, ay0 = 0.f, ax1 = 0.f, ay1 = 0.f;
    int i = 0;
    for (; i + 4 <= cnt; i += 4) {
        float2 p0 = csr[o + i],     p1 = csr[o + i + 1];
        float2 p2 = csr[o + i + 2], p3 = csr[o + i + 3];
        unsigned g0 = h1[(size_t)__float_as_int(p0.x) * 64 + lane];
        unsigned g1 = h1[(size_t)__float_as_int(p1.x) * 64 + lane];
        unsigned g2 = h1[(size_t)__float_as_int(p2.x) * 64 + lane];
        unsigned g3 = h1[(size_t)__float_as_int(p3.x) * 64 + lane];
        ax0 += p0.y * bflo(g0); ay0 += p0.y * bfhi(g0);
        ax1 += p1.y * bflo(g1); ay1 += p1.y * bfhi(g1);
        ax0 += p2.y * bflo(g2); ay0 += p2.y * bfhi(g2);
        ax1 += p3.y * bflo(g3); ay1 += p3.y * bfhi(g3);
    }
    for (; i < cnt; i++) {
        float2 p = csr[o + i];
        unsigned g0 = h1[(size_t)__float_as_int(p.x) * 64 + lane];
        ax0 += p.y * bflo(g0); ay0 += p.y * bfhi(g0);
    }
    float rd = rsd[v];
    m2[(size_t)v * 64 + lane] = pack2bf((ax0 + ax1) * rd, (ay0 + ay1) * rd);
}

// ---------------- MFMA GEMM: A[N x K] bf16 row-major @ prepacked W -> C[N x 128] fp32 ----------------
template <int K>
__global__ __launch_bounds__(256) void k_gemm(const short* __restrict__ A,
                                              const short* __restrict__ PW,
                                              float* __restrict__ C) {
    int wv = threadIdx.x >> 6, lane = threadIdx.x & 63;
    int tile = blockIdx.x * 4 + wv;              // 16-row tile; grid = NN/64
    int m = lane & 15, quad = lane >> 4;
    int row = tile * 16 + m;
    bf16x8 a[K / 32];
#pragma unroll
    for (int kt = 0; kt < K / 32; kt++)
        a[kt] = *(const bf16x8*)(A + (size_t)row * K + kt * 32 + quad * 8);
#pragma unroll
    for (int nt = 0; nt < 8; nt++) {
        f32x4 acc = {0.f, 0.f, 0.f, 0.f};
#pragma unroll
        for (int kt = 0; kt < K / 32; kt++) {
            bf16x8 b = *(const bf16x8*)(PW + ((size_t)(kt * 8 + nt) * 64 + lane) * 8);
            acc = __builtin_amdgcn_mfma_f32_16x16x32_bf16(a[kt], b, acc, 0, 0, 0);
        }
        int col = nt * 16 + m;
        int r0 = tile * 16 + quad * 4;
#pragma unroll
        for (int r = 0; r < 4; r++)
            C[(size_t)(r0 + r) * HH + col] = acc[r];
    }
}

// ---------------- per-feature column partial sums (no atomics) ----------------
__global__ __launch_bounds__(256) void k_colstats(const float* __restrict__ h,
                                                  float* __restrict__ part) {
    int f = threadIdx.x & 127, half = threadIdx.x >> 7;
    int r0 = blockIdx.x * 512;                   // 256 blocks
    float s1 = 0.f, s2 = 0.f;
    for (int r = half; r < 512; r += 2) {
        float v = h[(size_t)(r0 + r) * HH + f];
        s1 += v; s2 += v * v;
    }
    __shared__ float sh[256];
    sh[threadIdx.x] = s1;
    __syncthreads();
    float t1 = (half == 0) ? s1 + sh[threadIdx.x + 128] : 0.f;
    __syncthreads();
    sh[threadIdx.x] = s2;
    __syncthreads();
    if (half == 0) {
        float t2 = s2 + sh[threadIdx.x + 128];
        part[blockIdx.x * 256 + f]       = t1;
        part[blockIdx.x * 256 + 128 + f] = t2;
    }
}

// ---------------- reduce partials + norm coefficients ----------------
__global__ void k_coef(const float* __restrict__ part, const float* __restrict__ gamma,
                       const float* __restrict__ beta, const float* __restrict__ alpha,
                       float* __restrict__ ab) {
    int t = threadIdx.x;                         // 256 threads
    float s = 0.f;
    for (int b = 0; b < 256; b++) s += part[b * 256 + t];
    __shared__ float sh[256];
    sh[t] = s;
    __syncthreads();
    if (t < 128) {
        float mu = sh[t] * (1.f / NN);
        float e2 = sh[128 + t] * (1.f / NN);
        float al = alpha[t];
        float var = e2 - (2.f * al - al * al) * mu * mu;
        float a = rsqrtf(var + EPSV) * gamma[t];
        ab[t] = a;
        ab[HH + t] = beta[t] - al * mu * a;
    }
}

// ---------------- fused norm + leaky-relu (+bf16 writeback) + per-graph readout ----------------
template <bool WRITE>
__global__ __launch_bounds__(256) void k_normro(const float* __restrict__ h,
                                                const float* __restrict__ ab,
                                                float* __restrict__ racc,
                                                unsigned* __restrict__ hbf) {
    int fp = threadIdx.x & 63;                   // feature pair
    int q  = threadIdx.x >> 6;                   // 0..3
    int node0 = blockIdx.x * 64;                 // 2048 blocks; 64 | 4096 -> one graph per block
    int g = node0 / PP;
    float a0 = ab[2 * fp], a1 = ab[2 * fp + 1];
    float b0 = ab[HH + 2 * fp], b1 = ab[HH + 2 * fp + 1];
    float s0 = 0.f, s1 = 0.f;
    for (int i = q; i < 64; i += 4) {
        size_t idx = (size_t)(node0 + i) * HH + 2 * fp;
        float2 v = *(const float2*)(h + idx);
        float x0 = fmaf(a0, v.x, b0); x0 = x0 > 0.f ? x0 : SLOPEV * x0;
        float x1 = fmaf(a1, v.y, b1); x1 = x1 > 0.f ? x1 : SLOPEV * x1;
        if (WRITE) hbf[(size_t)(node0 + i) * 64 + fp] = pack2bf(x0, x1);
        s0 += x0; s1 += x1;
    }
    __shared__ float sh[512];
    sh[threadIdx.x] = s0;
    sh[256 + threadIdx.x] = s1;
    __syncthreads();
    if (q == 0) {
        float t0 = s0 + sh[64 + fp] + sh[128 + fp] + sh[192 + fp];
        float t1 = s1 + sh[256 + 64 + fp] + sh[256 + 128 + fp] + sh[256 + 192 + fp];
        atomicAdd(&racc[g * HH + 2 * fp],     t0);
        atomicAdd(&racc[g * HH + 2 * fp + 1], t1);
    }
}

// ---------------- final head ----------------
__global__ void k_final(const float* __restrict__ racc1, const float* __restrict__ racc2,
                        const float* __restrict__ Wc, float* __restrict__ out) {
    int t = threadIdx.x;                         // 512 = 32*16
    int b = t >> 4, o = t & 15;
    float acc = 0.f;
    for (int f = 0; f < HH; f++) acc += racc1[b * HH + f] * Wc[o * (2 * HH) + f];
    for (int f = 0; f < HH; f++) acc += racc2[b * HH + f] * Wc[o * (2 * HH) + HH + f];
    out[t] = acc * (1.f / PP);
}

extern "C" void kernel_launch(void* const* d_in, const int* in_sizes, int n_in,
                              void* d_out, int out_size, void* d_ws, size_t ws_size,
                              hipStream_t stream) {
    const float* features = (const float*)d_in[0];
    const float* ew       = (const float*)d_in[1];
    const int*   src      = (const int*)d_in[2];
    const int*   dst      = (const int*)d_in[3];
    const float* W1       = (const float*)d_in[4];
    const float* W2       = (const float*)d_in[5];
    const float* Wc       = (const float*)d_in[6];
    const float* gamma1   = (const float*)d_in[7];
    const float* beta1    = (const float*)d_in[8];
    const float* alpha1   = (const float*)d_in[9];
    const float* gamma2   = (const float*)d_in[10];
    const float* beta2    = (const float*)d_in[11];
    const float* alpha2   = (const float*)d_in[12];
    float* out = (float*)d_out;

    char* w = (char*)d_ws;
    int*    deg_s  = (int*)(w + 0);                       // 512 KB
    int*    deg_d  = (int*)(w + (512u << 10));            // 512 KB (contiguous with deg_s)
    float*  rs_s   = (float*)(w + (1024u << 10));
    float*  rs_d   = (float*)(w + (1536u << 10));
    int*    offs   = (int*)(w + (2048u << 10));
    int*    cursor = (int*)(w + (2560u << 10));
    float*  part1  = (float*)(w + (3072u << 10));         // 256 KB
    float*  part2  = (float*)(w + (3328u << 10));         // 256 KB
    float*  ab1    = (float*)(w + (3584u << 10));         // 1 KB
    float*  ab2    = ab1 + 256;
    float*  racc1  = ab2 + 256;                           // 16 KB (contiguous with racc2)
    float*  racc2  = racc1 + BG * HH;
    unsigned short* pw1 = (unsigned short*)(w + (3686u << 10));  // 16 KB
    unsigned short* pw2 = pw1 + 64 * HH;                         // 32 KB
    float2*   csr  = (float2*)(w + (4u  << 20));          // 16 MB:  4..20 MB
    unsigned* mbuf = (unsigned*)(w + (20u << 20));        // 32 MB: 20..52 MB (m1 then m2)
    unsigned* h1bf = (unsigned*)(w + (52u << 20));        // 32 MB: 52..84 MB
    unsigned* fx   = (unsigned*)(w + (84u << 20));        // 16 MB @84 MB (dies before Rpre written)
    float*    Rpre = (float*)(w + (84u << 20));           // 64 MB: 84..148 MB

    hipMemsetAsync(deg_s, 0, 2 * NN * sizeof(int), stream);
    hipMemsetAsync(racc1, 0, 2 * BG * HH * sizeof(float), stream);

    // prep
    k_cvt<<<NN * IND / 2 / 256, 256, 0, stream>>>(features, fx);
    k_packw<64><<<4, 256, 0, stream>>>(W1, pw1);
    k_packw<128><<<8, 256, 0, stream>>>(W2, pw2);
    k_deg<<<EE / 256, 256, 0, stream>>>(src, dst, deg_s, deg_d);
    k_rsqrt<<<NN / 256, 256, 0, stream>>>(deg_s, deg_d, rs_s, rs_d);
    k_scan<<<1, 1024, 0, stream>>>(deg_d, offs, cursor);
    k_scatter<<<EE / 256, 256, 0, stream>>>(src, dst, ew, rs_s, cursor, csr);

    // ---- layer 1 ----
    k_agg1<<<NN / 8, 256, 0, stream>>>(fx, csr, offs, deg_d, rs_d, mbuf);
    k_gemm<64><<<NN / 64, 256, 0, stream>>>((const short*)mbuf, (const short*)pw1, Rpre);
    k_colstats<<<NN / 512, 256, 0, stream>>>(Rpre, part1);
    k_coef<<<1, 256, 0, stream>>>(part1, gamma1, beta1, alpha1, ab1);
    k_normro<true><<<NN / 64, 256, 0, stream>>>(Rpre, ab1, racc1, h1bf);

    // ---- layer 2 ----
    k_agg2<<<NN / 4, 256, 0, stream>>>(h1bf, csr, offs, deg_d, rs_d, mbuf);
    k_gemm<128><<<NN / 64, 256, 0, stream>>>((const short*)mbuf, (const short*)pw2, Rpre);
    k_colstats<<<NN / 512, 256, 0, stream>>>(Rpre, part2);
    k_coef<<<1, 256, 0, stream>>>(part2, gamma2, beta2, alpha2, ab2);
    k_normro<false><<<NN / 64, 256, 0, stream>>>(Rpre, ab2, racc2, nullptr);

    // ---- head ----
    k_final<<<1, 512, 0, stream>>>(racc1, racc2, Wc, out);
}

// Round 3
// 464.837 us; speedup vs baseline: 3.6767x; 1.7654x over previous
//
#include <hip/hip_runtime.h>
#include <hip/hip_fp16.h>

constexpr int NN   = 131072;   // total nodes
constexpr int PP   = 4096;     // nodes per graph
constexpr int BG   = 32;       // graphs
constexpr int EE   = 2097152;  // edges
constexpr int IND  = 64;
constexpr int HH   = 128;
constexpr int CAP  = 69632;    // per-graph edge slot capacity (mean 65536, +16 sigma)
constexpr float EPSV   = 1e-5f;
constexpr float SLOPEV = 0.01f;

typedef short bf16x8 __attribute__((ext_vector_type(8)));
typedef float f32x4  __attribute__((ext_vector_type(4)));

__device__ __forceinline__ unsigned f2bf(float f) {
    unsigned u = __float_as_uint(f);
    return (u + 0x7FFFu + ((u >> 16) & 1u)) >> 16;      // RNE
}
__device__ __forceinline__ unsigned pack2bf(float lo, float hi) {
    return f2bf(lo) | (f2bf(hi) << 16);
}
__device__ __forceinline__ float bflo(unsigned p) { return __uint_as_float(p << 16); }
__device__ __forceinline__ float bfhi(unsigned p) { return __uint_as_float(p & 0xFFFF0000u); }
__device__ __forceinline__ float w16(unsigned r) {
    return __half2float(__ushort_as_half((unsigned short)(r >> 16)));
}

// ---------------- init: graph cursors + readout accumulators ----------------
__global__ void k_init(int* __restrict__ gcur, float* __restrict__ racc) {
    int t = threadIdx.x;                       // 1024
    if (t < BG) gcur[t * 16] = t * CAP;
    for (int i = t; i < 2 * BG * HH; i += 1024) racc[i] = 0.f;
}

// ---------------- fp32 -> bf16-pair convert (features) ----------------
__global__ __launch_bounds__(256) void k_cvt(const float* __restrict__ in,
                                             unsigned* __restrict__ out) {
    int t = blockIdx.x * 256 + threadIdx.x;
    float2 v = ((const float2*)in)[t];
    out[t] = pack2bf(v.x, v.y);
}

// ---------------- W -> MFMA B-fragment prepack ----------------
template <int K>
__global__ void k_packw(const float* __restrict__ W, unsigned short* __restrict__ pw) {
    int t = blockIdx.x * 256 + threadIdx.x;
    if (t >= K * 16) return;
    int lane = t & 63, nt = (t >> 6) & 7, kt = t >> 9;
    int kbase = kt * 32 + ((lane >> 4) & 3) * 8;
    int col   = nt * 16 + (lane & 15);
    for (int j = 0; j < 8; j++)
        pw[t * 8 + j] = (unsigned short)f2bf(W[(kbase + j) * HH + col]);
}

// ---------------- pass 1: 32-way partition of edges by graph ----------------
__global__ __launch_bounds__(256) void k_part(const int* __restrict__ src,
                                              const int* __restrict__ dst,
                                              const float* __restrict__ ew,
                                              int* __restrict__ gcur,
                                              uint2* __restrict__ recs) {
    __shared__ int cnt[32];
    __shared__ int start[32];
    __shared__ int gbase[32];
    __shared__ uint2 stage[4096];
    int t = threadIdx.x;
    int ebase = blockIdx.x * 4096;
    if (t < 32) cnt[t] = 0;
    __syncthreads();
    int es[16]; int ed[16]; float ev[16];
#pragma unroll
    for (int k = 0; k < 16; k++) {
        int e = ebase + k * 256 + t;
        es[k] = src[e]; ed[k] = dst[e]; ev[k] = ew[e];
        atomicAdd(&cnt[es[k] >> 12], 1);
    }
    __syncthreads();
    if (t == 0) {
        int run = 0;
        for (int g = 0; g < 32; g++) { start[g] = run; run += cnt[g]; }
    }
    __syncthreads();
    if (t < 32) {
        gbase[t] = atomicAdd(&gcur[t * 16], cnt[t]);
        cnt[t] = start[t];                      // becomes cursor
    }
    __syncthreads();
#pragma unroll
    for (int k = 0; k < 16; k++) {
        int g = es[k] >> 12;
        int pos = atomicAdd(&cnt[g], 1);
        stage[pos] = make_uint2((unsigned)(es[k] & 4095) | ((unsigned)(ed[k] & 4095) << 12) |
                                ((unsigned)g << 24), __float_as_uint(ev[k]));
    }
    __syncthreads();
    for (int i = t; i < 4096; i += 256) {
        uint2 r = stage[i];
        int g = r.x >> 24;
        recs[gbase[g] + (i - start[g])] = r;
    }
}

// ---------------- pass 2: per-graph degrees + rsqrt + offsets + counting sort ----------------
__global__ __launch_bounds__(1024) void k_build(const uint2* __restrict__ recs,
                                                const int* __restrict__ gcur,
                                                float* __restrict__ rsd,
                                                int* __restrict__ degd,
                                                int* __restrict__ offs,
                                                unsigned* __restrict__ csr2) {
    __shared__ int hs[4096];                   // src hist -> rs_s floats (in place)
    __shared__ int hd[4096];                   // dst hist (kept)
    __shared__ int cur[4096];                  // sort cursors
    __shared__ int partial[1024];
    int t = threadIdx.x;
    int g = blockIdx.x;
    int n = gcur[g * 16] - g * CAP;
    const uint2* base = recs + (size_t)g * CAP;
#pragma unroll
    for (int j = 0; j < 4; j++) { hs[t * 4 + j] = 0; hd[t * 4 + j] = 0; }
    __syncthreads();
    for (int i = t; i < n; i += 1024) {
        unsigned lo = base[i].x;
        atomicAdd(&hs[lo & 4095], 1);
        atomicAdd(&hd[(lo >> 12) & 4095], 1);
    }
    __syncthreads();
    int a[4];
#pragma unroll
    for (int j = 0; j < 4; j++) a[j] = hd[t * 4 + j];
    int s = a[0] + a[1] + a[2] + a[3];
    partial[t] = s;
    // rs_s in place; rs_d/degd to global
#pragma unroll
    for (int j = 0; j < 4; j++) {
        int idx = t * 4 + j;
        int vs = hs[idx]; if (vs < 1) vs = 1;
        ((float*)hs)[idx] = rsqrtf((float)vs);
        int vd = a[j]; if (vd < 1) vd = 1;
        rsd[g * PP + idx]  = rsqrtf((float)vd);
        degd[g * PP + idx] = a[j];
    }
    __syncthreads();
    for (int off = 1; off < 1024; off <<= 1) {
        int v = partial[t];
        int add = (t >= off) ? partial[t - off] : 0;
        __syncthreads();
        partial[t] = v + add;
        __syncthreads();
    }
    int run = (t == 0) ? 0 : partial[t - 1];
#pragma unroll
    for (int j = 0; j < 4; j++) {
        int idx = t * 4 + j;
        offs[g * PP + idx] = g * CAP + run;
        cur[idx] = run;
        run += a[j];
    }
    __syncthreads();
    const float* rs_s = (const float*)hs;
    for (int i = t; i < n; i += 1024) {
        uint2 r = base[i];
        int sl = r.x & 4095, dl = (r.x >> 12) & 4095;
        int pos = atomicAdd(&cur[dl], 1);
        float wf = __uint_as_float(r.y) * rs_s[sl];
        unsigned hb = (unsigned)__half_as_ushort(__float2half(wf));
        csr2[(size_t)g * CAP + pos] = (unsigned)sl | (hb << 16);
    }
}

// ---------------- agg layer 1: half-wave per node, bf16 gather ----------------
__global__ __launch_bounds__(256) void k_agg1(const unsigned* __restrict__ fx,   // [NN*32]
                                              const unsigned* __restrict__ csr2,
                                              const int* __restrict__ offs,
                                              const int* __restrict__ degd,
                                              const float* __restrict__ rsd,
                                              unsigned* __restrict__ m1) {      // [NN*32]
    int bid = blockIdx.x;                       // NN/8 blocks
    int xcd = bid & 7, idx = bid >> 3;
    int g = xcd * 4 + (idx >> 9);
    int node0 = g * PP + (idx & 511) * 8;
    int lane = threadIdx.x & 63, wv = threadIdx.x >> 6;
    int half = lane >> 5, sl = lane & 31;
    int v = node0 + wv * 2 + half;
    int o = offs[v], cnt = degd[v];
    unsigned fb = (unsigned)(v & ~(PP - 1)) * 32;       // graph feature base
    float ax0 = 0.f, ay0 = 0.f, ax1 = 0.f, ay1 = 0.f;
    int i = 0;
    for (; i + 4 <= cnt; i += 4) {
        unsigned r0 = csr2[o + i],     r1 = csr2[o + i + 1];
        unsigned r2 = csr2[o + i + 2], r3 = csr2[o + i + 3];
        unsigned g0 = fx[fb + (r0 & 4095) * 32 + sl];
        unsigned g1 = fx[fb + (r1 & 4095) * 32 + sl];
        unsigned g2 = fx[fb + (r2 & 4095) * 32 + sl];
        unsigned g3 = fx[fb + (r3 & 4095) * 32 + sl];
        float w0 = w16(r0), w1 = w16(r1), w2 = w16(r2), w3 = w16(r3);
        ax0 += w0 * bflo(g0); ay0 += w0 * bfhi(g0);
        ax1 += w1 * bflo(g1); ay1 += w1 * bfhi(g1);
        ax0 += w2 * bflo(g2); ay0 += w2 * bfhi(g2);
        ax1 += w3 * bflo(g3); ay1 += w3 * bfhi(g3);
    }
    for (; i < cnt; i++) {
        unsigned r = csr2[o + i];
        unsigned g0 = fx[fb + (r & 4095) * 32 + sl];
        float w = w16(r);
        ax0 += w * bflo(g0); ay0 += w * bfhi(g0);
    }
    float rd = rsd[v];
    m1[(size_t)v * 32 + sl] = pack2bf((ax0 + ax1) * rd, (ay0 + ay1) * rd);
}

// ---------------- agg layer 2: wave per node ----------------
__global__ __launch_bounds__(256) void k_agg2(const unsigned* __restrict__ h1,   // [NN*64]
                                              const unsigned* __restrict__ csr2,
                                              const int* __restrict__ offs,
                                              const int* __restrict__ degd,
                                              const float* __restrict__ rsd,
                                              unsigned* __restrict__ m2) {       // [NN*64]
    int bid = blockIdx.x;                        // NN/4 blocks
    int xcd = bid & 7, idx = bid >> 3;
    int g = xcd * 4 + (idx >> 10);
    int node0 = g * PP + (idx & 1023) * 4;
    int lane = threadIdx.x & 63, wv = threadIdx.x >> 6;
    int v = node0 + wv;
    int o = offs[v], cnt = degd[v];
    unsigned hb = (unsigned)(v & ~(PP - 1)) * 64;
    float ax0 = 0.f, ay0 = 0.f, ax1 = 0.f, ay1 = 0.f;
    int i = 0;
    for (; i + 4 <= cnt; i += 4) {
        unsigned r0 = csr2[o + i],     r1 = csr2[o + i + 1];
        unsigned r2 = csr2[o + i + 2], r3 = csr2[o + i + 3];
        unsigned g0 = h1[hb + (r0 & 4095) * 64 + lane];
        unsigned g1 = h1[hb + (r1 & 4095) * 64 + lane];
        unsigned g2 = h1[hb + (r2 & 4095) * 64 + lane];
        unsigned g3 = h1[hb + (r3 & 4095) * 64 + lane];
        float w0 = w16(r0), w1 = w16(r1), w2 = w16(r2), w3 = w16(r3);
        ax0 += w0 * bflo(g0); ay0 += w0 * bfhi(g0);
        ax1 += w1 * bflo(g1); ay1 += w1 * bfhi(g1);
        ax0 += w2 * bflo(g2); ay0 += w2 * bfhi(g2);
        ax1 += w3 * bflo(g3); ay1 += w3 * bfhi(g3);
    }
    for (; i < cnt; i++) {
        unsigned r = csr2[o + i];
        unsigned g0 = h1[hb + (r & 4095) * 64 + lane];
        float w = w16(r);
        ax0 += w * bflo(g0); ay0 += w * bfhi(g0);
    }
    float rd = rsd[v];
    m2[(size_t)v * 64 + lane] = pack2bf((ax0 + ax1) * rd, (ay0 + ay1) * rd);
}

// ---------------- MFMA GEMM + fused column-stat partials ----------------
template <int K>
__global__ __launch_bounds__(256) void k_gemm(const short* __restrict__ A,
                                              const short* __restrict__ PW,
                                              float* __restrict__ C,
                                              float* __restrict__ part) {
    __shared__ float s1[HH], s2[HH];
    int t = threadIdx.x;
    if (t < HH) { s1[t] = 0.f; s2[t] = 0.f; }
    __syncthreads();
    int wv = t >> 6, lane = t & 63;
    int tile = blockIdx.x * 4 + wv;              // 16-row tile; grid = NN/64
    int m = lane & 15, quad = lane >> 4;
    int row = tile * 16 + m;
    bf16x8 a[K / 32];
#pragma unroll
    for (int kt = 0; kt < K / 32; kt++)
        a[kt] = *(const bf16x8*)(A + (size_t)row * K + kt * 32 + quad * 8);
#pragma unroll
    for (int nt = 0; nt < 8; nt++) {
        f32x4 acc = {0.f, 0.f, 0.f, 0.f};
#pragma unroll
        for (int kt = 0; kt < K / 32; kt++) {
            bf16x8 b = *(const bf16x8*)(PW + ((size_t)(kt * 8 + nt) * 64 + lane) * 8);
            acc = __builtin_amdgcn_mfma_f32_16x16x32_bf16(a[kt], b, acc, 0, 0, 0);
        }
        int col = nt * 16 + m;
        int r0 = tile * 16 + quad * 4;
        float ps = 0.f, pq = 0.f;
#pragma unroll
        for (int r = 0; r < 4; r++) {
            C[(size_t)(r0 + r) * HH + col] = acc[r];
            ps += acc[r]; pq += acc[r] * acc[r];
        }
        atomicAdd(&s1[col], ps);
        atomicAdd(&s2[col], pq);
    }
    __syncthreads();
    if (t < HH) {
        part[blockIdx.x * 256 + t]      = s1[t];
        part[blockIdx.x * 256 + HH + t] = s2[t];
    }
}

// ---------------- stage-1 reduction of gemm partials ----------------
__global__ __launch_bounds__(256) void k_red(const float* __restrict__ part,
                                             float* __restrict__ pb) {
    int t = threadIdx.x, b = blockIdx.x;        // 64 blocks
    float s = 0.f;
    for (int r = 0; r < 32; r++) s += part[(size_t)(b * 32 + r) * 256 + t];
    pb[b * 256 + t] = s;
}

// ---------------- reduce + norm coefficients ----------------
__global__ void k_coef(const float* __restrict__ pb, const float* __restrict__ gamma,
                       const float* __restrict__ beta, const float* __restrict__ alpha,
                       float* __restrict__ ab) {
    int t = threadIdx.x;                         // 256 threads
    float s = 0.f;
    for (int b = 0; b < 64; b++) s += pb[b * 256 + t];
    __shared__ float sh[256];
    sh[t] = s;
    __syncthreads();
    if (t < 128) {
        float mu = sh[t] * (1.f / NN);
        float e2 = sh[128 + t] * (1.f / NN);
        float al = alpha[t];
        float var = e2 - (2.f * al - al * al) * mu * mu;
        float a = rsqrtf(var + EPSV) * gamma[t];
        ab[t] = a;
        ab[HH + t] = beta[t] - al * mu * a;
    }
}

// ---------------- fused norm + leaky-relu (+bf16 writeback) + per-graph readout ----------------
template <bool WRITE>
__global__ __launch_bounds__(256) void k_normro(const float* __restrict__ h,
                                                const float* __restrict__ ab,
                                                float* __restrict__ racc,
                                                unsigned* __restrict__ hbf) {
    int fp = threadIdx.x & 63;                   // feature pair
    int q  = threadIdx.x >> 6;                   // 0..3
    int node0 = blockIdx.x * 64;                 // one graph per block
    int g = node0 / PP;
    float a0 = ab[2 * fp], a1 = ab[2 * fp + 1];
    float b0 = ab[HH + 2 * fp], b1 = ab[HH + 2 * fp + 1];
    float s0 = 0.f, s1 = 0.f;
    for (int i = q; i < 64; i += 4) {
        size_t idx = (size_t)(node0 + i) * HH + 2 * fp;
        float2 v = *(const float2*)(h + idx);
        float x0 = fmaf(a0, v.x, b0); x0 = x0 > 0.f ? x0 : SLOPEV * x0;
        float x1 = fmaf(a1, v.y, b1); x1 = x1 > 0.f ? x1 : SLOPEV * x1;
        if (WRITE) hbf[(size_t)(node0 + i) * 64 + fp] = pack2bf(x0, x1);
        s0 += x0; s1 += x1;
    }
    __shared__ float sh[512];
    sh[threadIdx.x] = s0;
    sh[256 + threadIdx.x] = s1;
    __syncthreads();
    if (q == 0) {
        float t0 = s0 + sh[64 + fp] + sh[128 + fp] + sh[192 + fp];
        float t1 = s1 + sh[256 + 64 + fp] + sh[256 + 128 + fp] + sh[256 + 192 + fp];
        atomicAdd(&racc[g * HH + 2 * fp],     t0);
        atomicAdd(&racc[g * HH + 2 * fp + 1], t1);
    }
}

// ---------------- final head ----------------
__global__ void k_final(const float* __restrict__ racc1, const float* __restrict__ racc2,
                        const float* __restrict__ Wc, float* __restrict__ out) {
    int t = threadIdx.x;                         // 512 = 32*16
    int b = t >> 4, o = t & 15;
    float acc = 0.f;
    for (int f = 0; f < HH; f++) acc += racc1[b * HH + f] * Wc[o * (2 * HH) + f];
    for (int f = 0; f < HH; f++) acc += racc2[b * HH + f] * Wc[o * (2 * HH) + HH + f];
    out[t] = acc * (1.f / PP);
}

extern "C" void kernel_launch(void* const* d_in, const int* in_sizes, int n_in,
                              void* d_out, int out_size, void* d_ws, size_t ws_size,
                              hipStream_t stream) {
    const float* features = (const float*)d_in[0];
    const float* ew       = (const float*)d_in[1];
    const int*   src      = (const int*)d_in[2];
    const int*   dst      = (const int*)d_in[3];
    const float* W1       = (const float*)d_in[4];
    const float* W2       = (const float*)d_in[5];
    const float* Wc       = (const float*)d_in[6];
    const float* gamma1   = (const float*)d_in[7];
    const float* beta1    = (const float*)d_in[8];
    const float* alpha1   = (const float*)d_in[9];
    const float* gamma2   = (const float*)d_in[10];
    const float* beta2    = (const float*)d_in[11];
    const float* alpha2   = (const float*)d_in[12];
    float* out = (float*)d_out;

    char* w = (char*)d_ws;
    // misc block [0, 1 MB)
    int*    gcur   = (int*)(w + 0);                         // 32 * 16 ints (64B stride)
    float*  racc1  = (float*)(w + (16u << 10));             // 16 KB
    float*  racc2  = (float*)(w + (32u << 10));
    float*  ab1    = (float*)(w + (48u << 10));
    float*  ab2    = (float*)(w + (52u << 10));
    unsigned short* pw1 = (unsigned short*)(w + (64u << 10));   // 16 KB
    unsigned short* pw2 = (unsigned short*)(w + (80u << 10));   // 32 KB
    float*  pb     = (float*)(w + (128u << 10));            // 64 KB
    // arrays
    float*  rsd    = (float*)(w + (1024u << 10));           // 512 KB
    int*    degd   = (int*)(w + (1536u << 10));             // 512 KB
    int*    offs   = (int*)(w + (2048u << 10));             // 512 KB
    float*  part   = (float*)(w + (2560u << 10));           // 2 MB (2048*256 floats)
    unsigned* csr2 = (unsigned*)(w + (8u  << 20));          // 8.5 MB:  8..16.5
    unsigned* mbuf = (unsigned*)(w + (17u << 20));          // 32 MB: 17..49
    unsigned* h1bf = (unsigned*)(w + (49u << 20));          // 32 MB: 49..81
    float*    Rpre = (float*)(w + (81u << 20));             // 64 MB: 81..145
    uint2*    recs = (uint2*)(w + (81u << 20));             // 17 MB @81 (dead before gemm1)
    unsigned* fx   = (unsigned*)(w + (99u << 20));          // 16 MB @99 (dead before gemm1)

    // prep
    k_init<<<1, 1024, 0, stream>>>(gcur, racc1);            // racc1+racc2 contiguous
    k_cvt<<<NN * IND / 2 / 256, 256, 0, stream>>>(features, fx);
    k_packw<64><<<4, 256, 0, stream>>>(W1, pw1);
    k_packw<128><<<8, 256, 0, stream>>>(W2, pw2);
    k_part<<<EE / 4096, 256, 0, stream>>>(src, dst, ew, gcur, recs);
    k_build<<<BG, 1024, 0, stream>>>(recs, gcur, rsd, degd, offs, csr2);

    // ---- layer 1 ----
    k_agg1<<<NN / 8, 256, 0, stream>>>(fx, csr2, offs, degd, rsd, mbuf);
    k_gemm<64><<<NN / 64, 256, 0, stream>>>((const short*)mbuf, (const short*)pw1, Rpre, part);
    k_red<<<64, 256, 0, stream>>>(part, pb);
    k_coef<<<1, 256, 0, stream>>>(pb, gamma1, beta1, alpha1, ab1);
    k_normro<true><<<NN / 64, 256, 0, stream>>>(Rpre, ab1, racc1, h1bf);

    // ---- layer 2 ----
    k_agg2<<<NN / 4, 256, 0, stream>>>(h1bf, csr2, offs, degd, rsd, mbuf);
    k_gemm<128><<<NN / 64, 256, 0, stream>>>((const short*)mbuf, (const short*)pw2, Rpre, part);
    k_red<<<64, 256, 0, stream>>>(part, pb);
    k_coef<<<1, 256, 0, stream>>>(pb, gamma2, beta2, alpha2, ab2);
    k_normro<false><<<NN / 64, 256, 0, stream>>>(Rpre, ab2, racc2, nullptr);

    // ---- head ----
    k_final<<<1, 512, 0, stream>>>(racc1, racc2, Wc, out);
}

// Round 4
// 424.402 us; speedup vs baseline: 4.0270x; 1.0953x over previous
//
#include <hip/hip_runtime.h>
#include <hip/hip_fp16.h>

constexpr int NN   = 131072;   // total nodes
constexpr int PP   = 4096;     // nodes per graph
constexpr int BG   = 32;       // graphs
constexpr int EE   = 2097152;  // edges
constexpr int IND  = 64;
constexpr int HH   = 128;
constexpr int CAP  = 69632;    // per-graph edge slot capacity (mean 65536, +16 sigma)
constexpr float EPSV   = 1e-5f;
constexpr float SLOPEV = 0.01f;

typedef short bf16x8 __attribute__((ext_vector_type(8)));
typedef float f32x4  __attribute__((ext_vector_type(4)));

__device__ __forceinline__ unsigned f2bf(float f) {
    unsigned u = __float_as_uint(f);
    return (u + 0x7FFFu + ((u >> 16) & 1u)) >> 16;      // RNE
}
__device__ __forceinline__ unsigned pack2bf(float lo, float hi) {
    return f2bf(lo) | (f2bf(hi) << 16);
}
__device__ __forceinline__ float bflo(unsigned p) { return __uint_as_float(p << 16); }
__device__ __forceinline__ float bfhi(unsigned p) { return __uint_as_float(p & 0xFFFF0000u); }
__device__ __forceinline__ float w16(unsigned r) {
    return __half2float(__ushort_as_half((unsigned short)(r >> 16)));
}

// ---------------- W -> MFMA B-fragment prepack (device body) ----------------
template <int K>
__device__ __forceinline__ void packw_body(const float* __restrict__ W,
                                           unsigned short* __restrict__ pw, int t) {
    if (t >= K * 16) return;
    int lane = t & 63, nt = (t >> 6) & 7, kt = t >> 9;
    int kbase = kt * 32 + ((lane >> 4) & 3) * 8;
    int col   = nt * 16 + (lane & 15);
    for (int j = 0; j < 8; j++)
        pw[t * 8 + j] = (unsigned short)f2bf(W[(kbase + j) * HH + col]);
}

// ---------------- fused prep: feature cvt + init + weight prepack ----------------
__global__ __launch_bounds__(256) void k_prep(const float* __restrict__ features,
                                              unsigned* __restrict__ fx,
                                              const float* __restrict__ W1,
                                              unsigned short* __restrict__ pw1,
                                              const float* __restrict__ W2,
                                              unsigned short* __restrict__ pw2,
                                              int* __restrict__ gcur,
                                              float* __restrict__ racc) {
    int b = blockIdx.x, t = threadIdx.x;
    if (b < 16384) {                    // bf16 convert: NN*IND/2 = 16384*256 words
        int i = b * 256 + t;
        float2 v = ((const float2*)features)[i];
        fx[i] = pack2bf(v.x, v.y);
        return;
    }
    if (b == 16384) {                   // init cursors + readout accumulators
        if (t < BG) gcur[t * 16] = t * CAP;
        for (int i = t; i < 2 * BG * HH; i += 256) racc[i] = 0.f;
        return;
    }
    if (b < 16389) { packw_body<64>(W1, pw1, (b - 16385) * 256 + t); return; }
    packw_body<128>(W2, pw2, (b - 16389) * 256 + t);
}

// ---------------- pass 1: 32-way partition of edges by graph ----------------
__global__ __launch_bounds__(256) void k_part(const int* __restrict__ src,
                                              const int* __restrict__ dst,
                                              const float* __restrict__ ew,
                                              int* __restrict__ gcur,
                                              uint2* __restrict__ recs) {
    __shared__ int cnt[32];
    __shared__ int start[32];
    __shared__ int gbase[32];
    __shared__ uint2 stage[4096];
    int t = threadIdx.x;
    int ebase = blockIdx.x * 4096;
    if (t < 32) cnt[t] = 0;
    __syncthreads();
    int es[16]; int ed[16]; float ev[16];
#pragma unroll
    for (int k = 0; k < 16; k++) {
        int e = ebase + k * 256 + t;
        es[k] = src[e]; ed[k] = dst[e]; ev[k] = ew[e];
        atomicAdd(&cnt[es[k] >> 12], 1);
    }
    __syncthreads();
    if (t == 0) {
        int run = 0;
        for (int g = 0; g < 32; g++) { start[g] = run; run += cnt[g]; }
    }
    __syncthreads();
    if (t < 32) {
        gbase[t] = atomicAdd(&gcur[t * 16], cnt[t]);
        cnt[t] = start[t];                      // becomes cursor
    }
    __syncthreads();
#pragma unroll
    for (int k = 0; k < 16; k++) {
        int g = es[k] >> 12;
        int pos = atomicAdd(&cnt[g], 1);
        stage[pos] = make_uint2((unsigned)(es[k] & 4095) | ((unsigned)(ed[k] & 4095) << 12) |
                                ((unsigned)g << 24), __float_as_uint(ev[k]));
    }
    __syncthreads();
    for (int i = t; i < 4096; i += 256) {
        uint2 r = stage[i];
        int g = r.x >> 24;
        recs[gbase[g] + (i - start[g])] = r;
    }
}

// ---------------- build phase A: per-(graph,chunk) histograms ----------------
__global__ __launch_bounds__(1024) void k_hist(const uint2* __restrict__ recs,
                                               const int* __restrict__ gcur,
                                               int* __restrict__ shist,
                                               int* __restrict__ dhist) {
    __shared__ int hs[4096];
    __shared__ int hd[4096];
    int t = threadIdx.x;
    int g = blockIdx.x >> 3, c = blockIdx.x & 7;
    int n = gcur[g * 16] - g * CAP;
    int lo = (n * c) >> 3, hi = (n * (c + 1)) >> 3;
    ((int4*)hs)[t] = make_int4(0, 0, 0, 0);
    ((int4*)hd)[t] = make_int4(0, 0, 0, 0);
    __syncthreads();
    const uint2* base = recs + (size_t)g * CAP;
    for (int i = lo + t; i < hi; i += 1024) {
        unsigned x = base[i].x;
        atomicAdd(&hs[x & 4095], 1);
        atomicAdd(&hd[(x >> 12) & 4095], 1);
    }
    __syncthreads();
    ((int4*)(shist + (size_t)blockIdx.x * 4096))[t] = ((int4*)hs)[t];
    ((int4*)(dhist + (size_t)blockIdx.x * 4096))[t] = ((int4*)hd)[t];
}

// ---------------- build phase B: degrees, rsqrt, offsets, chunk cursor bases ----------------
__global__ __launch_bounds__(1024) void k_offs(int* __restrict__ shist,
                                               int* __restrict__ dhist,
                                               float* __restrict__ rs_s,
                                               float* __restrict__ rsd,
                                               int* __restrict__ degd,
                                               int* __restrict__ offs) {
    __shared__ int partial[1024];
    int t = threadIdx.x, g = blockIdx.x;
    int sdeg[4] = {0, 0, 0, 0}, ddeg[4] = {0, 0, 0, 0};
#pragma unroll
    for (int c = 0; c < 8; c++) {
        int4 sv = ((const int4*)(shist + (size_t)(g * 8 + c) * 4096))[t];
        int4 dv = ((const int4*)(dhist + (size_t)(g * 8 + c) * 4096))[t];
        sdeg[0] += sv.x; sdeg[1] += sv.y; sdeg[2] += sv.z; sdeg[3] += sv.w;
        ddeg[0] += dv.x; ddeg[1] += dv.y; ddeg[2] += dv.z; ddeg[3] += dv.w;
    }
#pragma unroll
    for (int j = 0; j < 4; j++) {
        int idx = t * 4 + j;
        int vs = sdeg[j]; if (vs < 1) vs = 1;
        rs_s[g * PP + idx] = rsqrtf((float)vs);
        int vd = ddeg[j]; if (vd < 1) vd = 1;
        rsd[g * PP + idx]  = rsqrtf((float)vd);
        degd[g * PP + idx] = ddeg[j];
    }
    partial[t] = ddeg[0] + ddeg[1] + ddeg[2] + ddeg[3];
    __syncthreads();
    for (int off = 1; off < 1024; off <<= 1) {
        int v = partial[t];
        int add = (t >= off) ? partial[t - off] : 0;
        __syncthreads();
        partial[t] = v + add;
        __syncthreads();
    }
    int run = (t == 0) ? 0 : partial[t - 1];
#pragma unroll
    for (int j = 0; j < 4; j++) {
        int idx = t * 4 + j;
        offs[g * PP + idx] = g * CAP + run;
        int nb = run;
        for (int c = 0; c < 8; c++) {
            size_t hidx = (size_t)(g * 8 + c) * 4096 + idx;
            int v = dhist[hidx];
            dhist[hidx] = nb;                 // per-chunk cursor base (graph-relative)
            nb += v;
        }
        run = nb;
    }
}

// ---------------- build phase C: counting-sort placement ----------------
__global__ __launch_bounds__(1024) void k_place(const uint2* __restrict__ recs,
                                                const int* __restrict__ gcur,
                                                const int* __restrict__ dhist,
                                                const float* __restrict__ rs_s,
                                                unsigned* __restrict__ csr2) {
    __shared__ int cur[4096];
    __shared__ float rss[4096];
    int t = threadIdx.x;
    int g = blockIdx.x >> 3, c = blockIdx.x & 7;
    int n = gcur[g * 16] - g * CAP;
    int lo = (n * c) >> 3, hi = (n * (c + 1)) >> 3;
    ((int4*)cur)[t] = ((const int4*)(dhist + (size_t)blockIdx.x * 4096))[t];
    ((float4*)rss)[t] = ((const float4*)(rs_s + (size_t)g * PP))[t];
    __syncthreads();
    const uint2* base = recs + (size_t)g * CAP;
    unsigned* cbase = csr2 + (size_t)g * CAP;
    for (int i = lo + t; i < hi; i += 1024) {
        uint2 r = base[i];
        int sl = r.x & 4095, dl = (r.x >> 12) & 4095;
        int pos = atomicAdd(&cur[dl], 1);
        float wf = __uint_as_float(r.y) * rss[sl];
        cbase[pos] = (unsigned)sl | ((unsigned)__half_as_ushort(__float2half(wf)) << 16);
    }
}

// ---------------- agg layer 1: half-wave per node, bf16 gather ----------------
__global__ __launch_bounds__(256) void k_agg1(const unsigned* __restrict__ fx,   // [NN*32]
                                              const unsigned* __restrict__ csr2,
                                              const int* __restrict__ offs,
                                              const int* __restrict__ degd,
                                              const float* __restrict__ rsd,
                                              unsigned* __restrict__ m1) {      // [NN*32]
    int bid = blockIdx.x;                       // NN/8 blocks
    int xcd = bid & 7, idx = bid >> 3;
    int g = xcd * 4 + (idx >> 9);
    int node0 = g * PP + (idx & 511) * 8;
    int lane = threadIdx.x & 63, wv = threadIdx.x >> 6;
    int half = lane >> 5, sl = lane & 31;
    int v = node0 + wv * 2 + half;
    int o = offs[v], cnt = degd[v];
    unsigned fb = (unsigned)(v & ~(PP - 1)) * 32;       // graph feature base
    float ax0 = 0.f, ay0 = 0.f, ax1 = 0.f, ay1 = 0.f;
    int i = 0;
    for (; i + 4 <= cnt; i += 4) {
        unsigned r0 = csr2[o + i],     r1 = csr2[o + i + 1];
        unsigned r2 = csr2[o + i + 2], r3 = csr2[o + i + 3];
        unsigned g0 = fx[fb + (r0 & 4095) * 32 + sl];
        unsigned g1 = fx[fb + (r1 & 4095) * 32 + sl];
        unsigned g2 = fx[fb + (r2 & 4095) * 32 + sl];
        unsigned g3 = fx[fb + (r3 & 4095) * 32 + sl];
        float w0 = w16(r0), w1 = w16(r1), w2 = w16(r2), w3 = w16(r3);
        ax0 += w0 * bflo(g0); ay0 += w0 * bfhi(g0);
        ax1 += w1 * bflo(g1); ay1 += w1 * bfhi(g1);
        ax0 += w2 * bflo(g2); ay0 += w2 * bfhi(g2);
        ax1 += w3 * bflo(g3); ay1 += w3 * bfhi(g3);
    }
    for (; i < cnt; i++) {
        unsigned r = csr2[o + i];
        unsigned g0 = fx[fb + (r & 4095) * 32 + sl];
        float w = w16(r);
        ax0 += w * bflo(g0); ay0 += w * bfhi(g0);
    }
    float rd = rsd[v];
    m1[(size_t)v * 32 + sl] = pack2bf((ax0 + ax1) * rd, (ay0 + ay1) * rd);
}

// ---------------- agg layer 2: wave per node ----------------
__global__ __launch_bounds__(256) void k_agg2(const unsigned* __restrict__ h1,   // [NN*64]
                                              const unsigned* __restrict__ csr2,
                                              const int* __restrict__ offs,
                                              const int* __restrict__ degd,
                                              const float* __restrict__ rsd,
                                              unsigned* __restrict__ m2) {       // [NN*64]
    int bid = blockIdx.x;                        // NN/4 blocks
    int xcd = bid & 7, idx = bid >> 3;
    int g = xcd * 4 + (idx >> 10);
    int node0 = g * PP + (idx & 1023) * 4;
    int lane = threadIdx.x & 63, wv = threadIdx.x >> 6;
    int v = node0 + wv;
    int o = offs[v], cnt = degd[v];
    unsigned hb = (unsigned)(v & ~(PP - 1)) * 64;
    float ax0 = 0.f, ay0 = 0.f, ax1 = 0.f, ay1 = 0.f;
    int i = 0;
    for (; i + 4 <= cnt; i += 4) {
        unsigned r0 = csr2[o + i],     r1 = csr2[o + i + 1];
        unsigned r2 = csr2[o + i + 2], r3 = csr2[o + i + 3];
        unsigned g0 = h1[hb + (r0 & 4095) * 64 + lane];
        unsigned g1 = h1[hb + (r1 & 4095) * 64 + lane];
        unsigned g2 = h1[hb + (r2 & 4095) * 64 + lane];
        unsigned g3 = h1[hb + (r3 & 4095) * 64 + lane];
        float w0 = w16(r0), w1 = w16(r1), w2 = w16(r2), w3 = w16(r3);
        ax0 += w0 * bflo(g0); ay0 += w0 * bfhi(g0);
        ax1 += w1 * bflo(g1); ay1 += w1 * bfhi(g1);
        ax0 += w2 * bflo(g2); ay0 += w2 * bfhi(g2);
        ax1 += w3 * bflo(g3); ay1 += w3 * bfhi(g3);
    }
    for (; i < cnt; i++) {
        unsigned r = csr2[o + i];
        unsigned g0 = h1[hb + (r & 4095) * 64 + lane];
        float w = w16(r);
        ax0 += w * bflo(g0); ay0 += w * bfhi(g0);
    }
    float rd = rsd[v];
    m2[(size_t)v * 64 + lane] = pack2bf((ax0 + ax1) * rd, (ay0 + ay1) * rd);
}

// ---------------- MFMA GEMM (bf16 out) + fused column-stat partials ----------------
template <int K>
__global__ __launch_bounds__(256) void k_gemm(const short* __restrict__ A,
                                              const short* __restrict__ PW,
                                              unsigned short* __restrict__ C,   // bf16 out
                                              float* __restrict__ part) {
    __shared__ float s1[HH], s2[HH];
    int t = threadIdx.x;
    if (t < HH) { s1[t] = 0.f; s2[t] = 0.f; }
    __syncthreads();
    int wv = t >> 6, lane = t & 63;
    int tile = blockIdx.x * 4 + wv;              // 16-row tile; grid = NN/64
    int m = lane & 15, quad = lane >> 4;
    int row = tile * 16 + m;
    bf16x8 a[K / 32];
#pragma unroll
    for (int kt = 0; kt < K / 32; kt++)
        a[kt] = *(const bf16x8*)(A + (size_t)row * K + kt * 32 + quad * 8);
#pragma unroll
    for (int nt = 0; nt < 8; nt++) {
        f32x4 acc = {0.f, 0.f, 0.f, 0.f};
#pragma unroll
        for (int kt = 0; kt < K / 32; kt++) {
            bf16x8 b = *(const bf16x8*)(PW + ((size_t)(kt * 8 + nt) * 64 + lane) * 8);
            acc = __builtin_amdgcn_mfma_f32_16x16x32_bf16(a[kt], b, acc, 0, 0, 0);
        }
        int col = nt * 16 + m;
        int r0 = tile * 16 + quad * 4;
        float ps = 0.f, pq = 0.f;
#pragma unroll
        for (int r = 0; r < 4; r++) {
            C[(size_t)(r0 + r) * HH + col] = (unsigned short)f2bf(acc[r]);
            ps += acc[r]; pq += acc[r] * acc[r];
        }
        atomicAdd(&s1[col], ps);
        atomicAdd(&s2[col], pq);
    }
    __syncthreads();
    if (t < HH) {
        part[blockIdx.x * 256 + t]      = s1[t];
        part[blockIdx.x * 256 + HH + t] = s2[t];
    }
}

// ---------------- stage-1 reduction of gemm partials ----------------
__global__ __launch_bounds__(256) void k_red(const float* __restrict__ part,
                                             float* __restrict__ pb) {
    int t = threadIdx.x, b = blockIdx.x;        // 64 blocks
    float s = 0.f;
    for (int r = 0; r < 32; r++) s += part[(size_t)(b * 32 + r) * 256 + t];
    pb[b * 256 + t] = s;
}

// ---------------- reduce + norm coefficients ----------------
__global__ void k_coef(const float* __restrict__ pb, const float* __restrict__ gamma,
                       const float* __restrict__ beta, const float* __restrict__ alpha,
                       float* __restrict__ ab) {
    int t = threadIdx.x;                         // 256 threads
    float s = 0.f;
    for (int b = 0; b < 64; b++) s += pb[b * 256 + t];
    __shared__ float sh[256];
    sh[t] = s;
    __syncthreads();
    if (t < 128) {
        float mu = sh[t] * (1.f / NN);
        float e2 = sh[128 + t] * (1.f / NN);
        float al = alpha[t];
        float var = e2 - (2.f * al - al * al) * mu * mu;
        float a = rsqrtf(var + EPSV) * gamma[t];
        ab[t] = a;
        ab[HH + t] = beta[t] - al * mu * a;
    }
}

// ---------------- fused norm + leaky-relu (in-place bf16) + per-graph readout ----------------
template <bool WRITE>
__global__ __launch_bounds__(256) void k_normro(unsigned* __restrict__ h,       // bf16 pairs
                                                const float* __restrict__ ab,
                                                float* __restrict__ racc) {
    int fp = threadIdx.x & 63;                   // feature pair
    int q  = threadIdx.x >> 6;                   // 0..3
    int node0 = blockIdx.x * 64;                 // one graph per block
    int g = node0 / PP;
    float a0 = ab[2 * fp], a1 = ab[2 * fp + 1];
    float b0 = ab[HH + 2 * fp], b1 = ab[HH + 2 * fp + 1];
    float s0 = 0.f, s1 = 0.f;
    for (int i = q; i < 64; i += 4) {
        size_t idx = (size_t)(node0 + i) * 64 + fp;
        unsigned v = h[idx];
        float x0 = fmaf(a0, bflo(v), b0); x0 = x0 > 0.f ? x0 : SLOPEV * x0;
        float x1 = fmaf(a1, bfhi(v), b1); x1 = x1 > 0.f ? x1 : SLOPEV * x1;
        if (WRITE) h[idx] = pack2bf(x0, x1);
        s0 += x0; s1 += x1;
    }
    __shared__ float sh[512];
    sh[threadIdx.x] = s0;
    sh[256 + threadIdx.x] = s1;
    __syncthreads();
    if (q == 0) {
        float t0 = s0 + sh[64 + fp] + sh[128 + fp] + sh[192 + fp];
        float t1 = s1 + sh[256 + 64 + fp] + sh[256 + 128 + fp] + sh[256 + 192 + fp];
        atomicAdd(&racc[g * HH + 2 * fp],     t0);
        atomicAdd(&racc[g * HH + 2 * fp + 1], t1);
    }
}

// ---------------- final head ----------------
__global__ void k_final(const float* __restrict__ racc1, const float* __restrict__ racc2,
                        const float* __restrict__ Wc, float* __restrict__ out) {
    int t = threadIdx.x;                         // 512 = 32*16
    int b = t >> 4, o = t & 15;
    float acc = 0.f;
    for (int f = 0; f < HH; f++) acc += racc1[b * HH + f] * Wc[o * (2 * HH) + f];
    for (int f = 0; f < HH; f++) acc += racc2[b * HH + f] * Wc[o * (2 * HH) + HH + f];
    out[t] = acc * (1.f / PP);
}

extern "C" void kernel_launch(void* const* d_in, const int* in_sizes, int n_in,
                              void* d_out, int out_size, void* d_ws, size_t ws_size,
                              hipStream_t stream) {
    const float* features = (const float*)d_in[0];
    const float* ew       = (const float*)d_in[1];
    const int*   src      = (const int*)d_in[2];
    const int*   dst      = (const int*)d_in[3];
    const float* W1       = (const float*)d_in[4];
    const float* W2       = (const float*)d_in[5];
    const float* Wc       = (const float*)d_in[6];
    const float* gamma1   = (const float*)d_in[7];
    const float* beta1    = (const float*)d_in[8];
    const float* alpha1   = (const float*)d_in[9];
    const float* gamma2   = (const float*)d_in[10];
    const float* beta2    = (const float*)d_in[11];
    const float* alpha2   = (const float*)d_in[12];
    float* out = (float*)d_out;

    char* w = (char*)d_ws;
    // misc block [0, 1 MB)
    int*    gcur   = (int*)(w + 0);                         // 32 * 16 ints
    float*  racc1  = (float*)(w + (16u << 10));             // 16 KB
    float*  racc2  = (float*)(w + (32u << 10));             // contiguous with racc1
    float*  ab1    = (float*)(w + (48u << 10));
    float*  ab2    = (float*)(w + (52u << 10));
    unsigned short* pw1 = (unsigned short*)(w + (64u << 10));   // 16 KB
    unsigned short* pw2 = (unsigned short*)(w + (80u << 10));   // 32 KB
    float*  pb     = (float*)(w + (128u << 10));            // 64 KB
    // arrays
    float*  rs_s   = (float*)(w + (1024u << 10));           // 512 KB
    float*  rsd    = (float*)(w + (1536u << 10));           // 512 KB
    int*    degd   = (int*)(w + (2048u << 10));             // 512 KB
    int*    offs   = (int*)(w + (2560u << 10));             // 512 KB
    float*  part   = (float*)(w + (3u << 20));              // 2 MB: 3..5
    int*    shist  = (int*)(w + (5u << 20));                // 4 MB: 5..9
    int*    dhist  = (int*)(w + (9u << 20));                // 4 MB: 9..13
    unsigned* csr2 = (unsigned*)(w + (13u << 20));          // 8.5 MB: 13..21.5
    unsigned* mbuf = (unsigned*)(w + (22u << 20));          // 32 MB: 22..54
    unsigned* hbuf = (unsigned*)(w + (54u << 20));          // 32 MB: 54..86
    uint2*    recs = (uint2*)(w + (86u << 20));             // 17 MB: 86..103
    unsigned* fx   = (unsigned*)(w + (104u << 20));         // 16 MB: 104..120

    // prep (cvt + init + packw fused)
    k_prep<<<16397, 256, 0, stream>>>(features, fx, W1, pw1, W2, pw2, gcur, racc1);

    // CSR build
    k_part<<<EE / 4096, 256, 0, stream>>>(src, dst, ew, gcur, recs);
    k_hist<<<BG * 8, 1024, 0, stream>>>(recs, gcur, shist, dhist);
    k_offs<<<BG, 1024, 0, stream>>>(shist, dhist, rs_s, rsd, degd, offs);
    k_place<<<BG * 8, 1024, 0, stream>>>(recs, gcur, dhist, rs_s, csr2);

    // ---- layer 1 ----
    k_agg1<<<NN / 8, 256, 0, stream>>>(fx, csr2, offs, degd, rsd, mbuf);
    k_gemm<64><<<NN / 64, 256, 0, stream>>>((const short*)mbuf, (const short*)pw1,
                                            (unsigned short*)hbuf, part);
    k_red<<<64, 256, 0, stream>>>(part, pb);
    k_coef<<<1, 256, 0, stream>>>(pb, gamma1, beta1, alpha1, ab1);
    k_normro<true><<<NN / 64, 256, 0, stream>>>(hbuf, ab1, racc1);

    // ---- layer 2 ----
    k_agg2<<<NN / 4, 256, 0, stream>>>(hbuf, csr2, offs, degd, rsd, mbuf);
    k_gemm<128><<<NN / 64, 256, 0, stream>>>((const short*)mbuf, (const short*)pw2,
                                             (unsigned short*)hbuf, part);
    k_red<<<64, 256, 0, stream>>>(part, pb);
    k_coef<<<1, 256, 0, stream>>>(pb, gamma2, beta2, alpha2, ab2);
    k_normro<false><<<NN / 64, 256, 0, stream>>>(hbuf, ab2, racc2);

    // ---- head ----
    k_final<<<1, 512, 0, stream>>>(racc1, racc2, Wc, out);
}